// Round 13
// baseline (319.527 us; speedup 1.0000x reference)
//
#include <hip/hip_runtime.h>
#include <math.h>

#define N_NODES 50000
#define N_EDGES 800000
#define IN_DIM 128
#define HIDDEN 128
#define CLASSES 64
#define N2 100000      // concatenated node space: graph1 [0,50000), graph2 [50000,100000)

#define BIN_SHIFT 8    // 256 nodes per bin
#define BIN_SZ 256
#define NB 391         // ceil(100000/256)
#define NBLK 256       // edge-partition blocks for P1/P2
#define CHUNK ((2 * N_EDGES + NBLK - 1) / NBLK)

#define NSTRIP 3125    // 50000 / 16 rows per MFMA strip
#define GBLK 391       // ceil(3125 / 8 strips per block)

typedef __attribute__((ext_vector_type(8))) short bf16x8;
typedef __attribute__((ext_vector_type(4))) float f32x4;

union FragU {
    uint4 u4;
    uint2 u2[2];
    bf16x8 f;
};

static __device__ __forceinline__ float elu_f(float x) {
    return x > 0.f ? x : (expf(x) - 1.f);
}

// f32 -> bf16 (RNE) pack of two values into one uint (lo = first)
static __device__ __forceinline__ unsigned pack_bf2(float a, float b) {
    unsigned ua = __float_as_uint(a);
    ua = (ua + 0x7FFFu + ((ua >> 16) & 1u)) >> 16;
    unsigned ub = __float_as_uint(b);
    ub = (ub + 0x7FFFu + ((ub >> 16) & 1u)) >> 16;
    return ua | (ub << 16);
}

static __device__ __forceinline__ void addf4(float4& a, const float4 b) {
    a.x += b.x; a.y += b.y; a.z += b.z; a.w += b.w;
}

// ---------------------------------------------------------------------------
// P1: per-block LDS histogram over bins. counts[bin*NBLK + blk] (bin-major).
// ---------------------------------------------------------------------------
__global__ __launch_bounds__(1024) void k_p1_count(
    const int* __restrict__ dst1, const int* __restrict__ dst2,
    int* __restrict__ counts)
{
    __shared__ int hist[NB];
    const int t = threadIdx.x, b = blockIdx.x;
    if (t < NB) hist[t] = 0;
    __syncthreads();
    const int beg = b * CHUNK;
    const int end = min(beg + CHUNK, 2 * N_EDGES);
    for (int i = beg + t; i < end; i += 1024) {
        const int idx = (i < N_EDGES) ? dst1[i] : (N_NODES + dst2[i - N_EDGES]);
        atomicAdd(&hist[idx >> BIN_SHIFT], 1);
    }
    __syncthreads();
    if (t < NB) counts[t * NBLK + b] = hist[t];
}

// ---------------------------------------------------------------------------
// Scan: bin totals, exclusive scan over bins, in-place rewrite counts ->
// per-(bin,blk) start cursors. One 512-thread block.
// ---------------------------------------------------------------------------
__global__ __launch_bounds__(512) void k_scan_bins(
    int* __restrict__ counts, int* __restrict__ binStart, int* __restrict__ off)
{
    __shared__ int tot[512];
    const int t = threadIdx.x;
    int total = 0;
    if (t < NB) {
        const int4* p = reinterpret_cast<const int4*>(counts + t * NBLK);
        #pragma unroll 8
        for (int i = 0; i < NBLK / 4; ++i) {
            const int4 c = p[i];
            total += (c.x + c.y) + (c.z + c.w);
        }
    }
    tot[t] = (t < NB) ? total : 0;
    __syncthreads();
    const int v = tot[t];
    for (int d = 1; d < 512; d <<= 1) {
        const int x = (t >= d) ? tot[t - d] : 0;
        __syncthreads();
        tot[t] += x;
        __syncthreads();
    }
    const int excl = tot[t] - v;
    if (t < NB) binStart[t] = excl;
    if (t == NB - 1) binStart[NB] = tot[t];      // == 2*N_EDGES
    if (t == 0) off[N2] = 2 * N_EDGES;           // CSR sentinel
    if (t < NB) {
        int run = excl;
        int* p = counts + t * NBLK;
        for (int i = 0; i < NBLK; i += 4) {
            int4 c = *reinterpret_cast<int4*>(p + i);
            int4 w;
            w.x = run; run += c.x;
            w.y = run; run += c.y;
            w.z = run; run += c.z;
            w.w = run; run += c.w;
            *reinterpret_cast<int4*>(p + i) = w;
        }
    }
}

// ---------------------------------------------------------------------------
// P2: scatter packed records into per-(bin,blk) contiguous sub-ranges.
// rec = (src << 8) | localDst
// ---------------------------------------------------------------------------
__global__ __launch_bounds__(1024) void k_p2_scatter(
    const int* __restrict__ src1, const int* __restrict__ dst1,
    const int* __restrict__ src2, const int* __restrict__ dst2,
    const int* __restrict__ counts, unsigned* __restrict__ binned)
{
    __shared__ int cur[NB];
    const int t = threadIdx.x, b = blockIdx.x;
    if (t < NB) cur[t] = counts[t * NBLK + b];
    __syncthreads();
    const int beg = b * CHUNK;
    const int end = min(beg + CHUNK, 2 * N_EDGES);
    for (int i = beg + t; i < end; i += 1024) {
        int s, idx;
        if (i < N_EDGES) { s = src1[i]; idx = dst1[i]; }
        else             { s = src2[i - N_EDGES]; idx = N_NODES + dst2[i - N_EDGES]; }
        const int bin = idx >> BIN_SHIFT;
        const unsigned rec = ((unsigned)s << BIN_SHIFT) | (unsigned)(idx & (BIN_SZ - 1));
        const int pos = atomicAdd(&cur[bin], 1);
        binned[pos] = rec;
    }
}

// ---------------------------------------------------------------------------
// P3: per-bin CSR build. LDS hist(256) + scan -> off; scatter srcs.
// ---------------------------------------------------------------------------
__global__ __launch_bounds__(1024) void k_p3_csr(
    const unsigned* __restrict__ binned, const int* __restrict__ binStart,
    int* __restrict__ off, int* __restrict__ csr)
{
    __shared__ int hist[BIN_SZ], sc[BIN_SZ], cur[BIN_SZ];
    const int t = threadIdx.x, bin = blockIdx.x;
    const int bs = binStart[bin], be = binStart[bin + 1];
    const int base = bin << BIN_SHIFT;
    const int nloc = min(BIN_SZ, N2 - base);
    if (t < BIN_SZ) hist[t] = 0;
    __syncthreads();
    for (int p = bs + t; p < be; p += 1024)
        atomicAdd(&hist[binned[p] & (BIN_SZ - 1u)], 1);
    __syncthreads();
    int v = 0;
    if (t < BIN_SZ) { v = hist[t]; sc[t] = v; }
    __syncthreads();
    for (int d = 1; d < BIN_SZ; d <<= 1) {
        int x = 0;
        if (t < BIN_SZ && t >= d) x = sc[t - d];
        __syncthreads();
        if (t < BIN_SZ) sc[t] += x;
        __syncthreads();
    }
    if (t < BIN_SZ) {
        const int excl = sc[t] - v;
        cur[t] = bs + excl;
        if (t < nloc) off[base + t] = bs + excl;
    }
    __syncthreads();
    for (int p = bs + t; p < be; p += 1024) {
        const unsigned rec = binned[p];
        const int pos = atomicAdd(&cur[rec & (BIN_SZ - 1u)], 1);
        csr[pos] = (int)(rec >> BIN_SHIFT);
    }
}

// ---------------------------------------------------------------------------
// GEMM 1 (MFMA): y1s = f32( f @ W1^T ), SLICED output
// y1s[s][node][16], s = dim>>4 — each slice is a contiguous 3.2 MB f32 slab.
// ---------------------------------------------------------------------------
__global__ __launch_bounds__(256) void k_gemm1(
    const float* __restrict__ f, const float* __restrict__ W1,
    float* __restrict__ y1s)
{
    __shared__ unsigned short Wl[HIDDEN][140];
    const int t = threadIdx.x;
    for (int i = t * 4; i < HIDDEN * IN_DIM; i += 1024) {
        const float4 w = *reinterpret_cast<const float4*>(W1 + i);
        const int o = i >> 7, k = i & 127;
        uint2 p;
        p.x = pack_bf2(w.x, w.y);
        p.y = pack_bf2(w.z, w.w);
        *reinterpret_cast<uint2*>(&Wl[o][k]) = p;
    }
    __syncthreads();

    const int wv = t >> 6;
    const int l  = t & 63;
    const int rc = l & 15;     // A-row / B-col / D-col
    const int kq = l >> 4;     // k-oct selector

    const int sid0 = (blockIdx.x * 4 + wv) * 2;
    const int sid1 = sid0 + 1;
    const bool v0 = sid0 < NSTRIP, v1 = sid1 < NSTRIP;
    const int m0 = min(sid0, NSTRIP - 1) * 16;
    const int m1 = min(sid1, NSTRIP - 1) * 16;

    f32x4 acc[2][8];
    #pragma unroll
    for (int st = 0; st < 2; ++st)
        #pragma unroll
        for (int nt = 0; nt < 8; ++nt)
            acc[st][nt] = (f32x4){0.f, 0.f, 0.f, 0.f};

    #pragma unroll
    for (int kc = 0; kc < 4; ++kc) {
        const int kbase = kc * 32 + kq * 8;
        const float* ap0 = f + (size_t)(m0 + rc) * IN_DIM + kbase;
        const float* ap1 = f + (size_t)(m1 + rc) * IN_DIM + kbase;
        const float4 fa0 = *reinterpret_cast<const float4*>(ap0);
        const float4 fa1 = *reinterpret_cast<const float4*>(ap0 + 4);
        const float4 fb0 = *reinterpret_cast<const float4*>(ap1);
        const float4 fb1 = *reinterpret_cast<const float4*>(ap1 + 4);
        FragU A0, A1;
        A0.u4.x = pack_bf2(fa0.x, fa0.y); A0.u4.y = pack_bf2(fa0.z, fa0.w);
        A0.u4.z = pack_bf2(fa1.x, fa1.y); A0.u4.w = pack_bf2(fa1.z, fa1.w);
        A1.u4.x = pack_bf2(fb0.x, fb0.y); A1.u4.y = pack_bf2(fb0.z, fb0.w);
        A1.u4.z = pack_bf2(fb1.x, fb1.y); A1.u4.w = pack_bf2(fb1.z, fb1.w);
        #pragma unroll
        for (int nt = 0; nt < 8; ++nt) {
            const unsigned short* bp = &Wl[nt * 16 + rc][kbase];
            FragU B;
            B.u2[0] = *reinterpret_cast<const uint2*>(bp);
            B.u2[1] = *reinterpret_cast<const uint2*>(bp + 4);
            acc[0][nt] = __builtin_amdgcn_mfma_f32_16x16x32_bf16(A0.f, B.f, acc[0][nt], 0, 0, 0);
            acc[1][nt] = __builtin_amdgcn_mfma_f32_16x16x32_bf16(A1.f, B.f, acc[1][nt], 0, 0, 0);
        }
    }

    #pragma unroll
    for (int st = 0; st < 2; ++st) {
        if (st == 0 ? !v0 : !v1) continue;
        const int mb = (st == 0 ? m0 : m1) + (l >> 4) * 4;
        #pragma unroll
        for (int nt = 0; nt < 8; ++nt) {
            #pragma unroll
            for (int r = 0; r < 4; ++r) {
                y1s[(((size_t)nt * N_NODES + (mb + r)) << 4) + rc] = acc[st][nt][r];
            }
        }
    }
}

// ---------------------------------------------------------------------------
// GEMM 2 (MFMA): y2s = f32( x1 @ W2^T ), SLICED output
// y2s[s][node][16], s = dim>>4 — each slice is a contiguous 3.2 MB f32 slab.
// ---------------------------------------------------------------------------
__global__ __launch_bounds__(256) void k_gemm2(
    const float* __restrict__ x1, const float* __restrict__ W2,
    float* __restrict__ y2s)
{
    __shared__ unsigned short Wl[CLASSES][140];
    const int t = threadIdx.x;
    for (int i = t * 4; i < CLASSES * IN_DIM; i += 1024) {
        const float4 w = *reinterpret_cast<const float4*>(W2 + i);
        const int o = i >> 7, k = i & 127;
        uint2 p;
        p.x = pack_bf2(w.x, w.y);
        p.y = pack_bf2(w.z, w.w);
        *reinterpret_cast<uint2*>(&Wl[o][k]) = p;
    }
    __syncthreads();

    const int wv = t >> 6;
    const int l  = t & 63;
    const int rc = l & 15;
    const int kq = l >> 4;

    const int sid0 = (blockIdx.x * 4 + wv) * 2;
    const int sid1 = sid0 + 1;
    const bool v0 = sid0 < NSTRIP, v1 = sid1 < NSTRIP;
    const int m0 = min(sid0, NSTRIP - 1) * 16;
    const int m1 = min(sid1, NSTRIP - 1) * 16;

    f32x4 acc[2][4];
    #pragma unroll
    for (int st = 0; st < 2; ++st)
        #pragma unroll
        for (int nt = 0; nt < 4; ++nt)
            acc[st][nt] = (f32x4){0.f, 0.f, 0.f, 0.f};

    #pragma unroll
    for (int kc = 0; kc < 4; ++kc) {
        const int kbase = kc * 32 + kq * 8;
        const float* ap0 = x1 + (size_t)(m0 + rc) * IN_DIM + kbase;
        const float* ap1 = x1 + (size_t)(m1 + rc) * IN_DIM + kbase;
        const float4 fa0 = *reinterpret_cast<const float4*>(ap0);
        const float4 fa1 = *reinterpret_cast<const float4*>(ap0 + 4);
        const float4 fb0 = *reinterpret_cast<const float4*>(ap1);
        const float4 fb1 = *reinterpret_cast<const float4*>(ap1 + 4);
        FragU A0, A1;
        A0.u4.x = pack_bf2(fa0.x, fa0.y); A0.u4.y = pack_bf2(fa0.z, fa0.w);
        A0.u4.z = pack_bf2(fa1.x, fa1.y); A0.u4.w = pack_bf2(fa1.z, fa1.w);
        A1.u4.x = pack_bf2(fb0.x, fb0.y); A1.u4.y = pack_bf2(fb0.z, fb0.w);
        A1.u4.z = pack_bf2(fb1.x, fb1.y); A1.u4.w = pack_bf2(fb1.z, fb1.w);
        #pragma unroll
        for (int nt = 0; nt < 4; ++nt) {
            const unsigned short* bp = &Wl[nt * 16 + rc][kbase];
            FragU B;
            B.u2[0] = *reinterpret_cast<const uint2*>(bp);
            B.u2[1] = *reinterpret_cast<const uint2*>(bp + 4);
            acc[0][nt] = __builtin_amdgcn_mfma_f32_16x16x32_bf16(A0.f, B.f, acc[0][nt], 0, 0, 0);
            acc[1][nt] = __builtin_amdgcn_mfma_f32_16x16x32_bf16(A1.f, B.f, acc[1][nt], 0, 0, 0);
        }
    }

    #pragma unroll
    for (int st = 0; st < 2; ++st) {
        if (st == 0 ? !v0 : !v1) continue;
        const int mb = (st == 0 ? m0 : m1) + (l >> 4) * 4;
        #pragma unroll
        for (int nt = 0; nt < 4; ++nt) {
            #pragma unroll
            for (int r = 0; r < 4; ++r) {
                y2s[(((size_t)nt * N_NODES + (mb + r)) << 4) + rc] = acc[st][nt][r];
            }
        }
    }
}

// ---------------------------------------------------------------------------
// Pull layer 1, 16-dim-sliced f32, XCD-affine, lane-group-serial (no shfls,
// no unpack). slice = blockIdx&7 (one 3.2 MB slab per XCD). Group of 4 lanes
// = one node's 16-dim slice (float4/lane); serial edge loop 8-wide unrolled.
// ---------------------------------------------------------------------------
__global__ __launch_bounds__(256) void k_pull1(
    const float* __restrict__ y1s,
    const int* __restrict__ off, const int* __restrict__ csr,
    const float* __restrict__ b1, const float* __restrict__ attn,
    float* __restrict__ x1)
{
    const int bid = blockIdx.x;
    const int sl = bid & 7;                      // slice 0..7
    const int nb = bid >> 3;                     // node-block 0..781
    const int t = threadIdx.x;
    const int lane = t & 63;
    const int grp = lane >> 2;                   // node within wave 0..15
    const int c4 = (lane & 3) * 4;               // dims [c4,c4+4) of slice
    const int v = nb * 64 + (t >> 6) * 16 + grp;
    if (v >= N_NODES) return;
    const float* yb = y1s + ((size_t)sl * N_NODES << 4);

    float4 tot1 = {0.f, 0.f, 0.f, 0.f}, tot2 = {0.f, 0.f, 0.f, 0.f};
    #pragma unroll
    for (int g = 0; g < 2; ++g) {
        const int idx = g * N_NODES + v;
        const int beg = off[idx], end_ = off[idx + 1];
        float4 acc = {0.f, 0.f, 0.f, 0.f};
        int j = beg;
        for (; j + 8 <= end_; j += 8) {
            const int s0 = csr[j],     s1 = csr[j + 1];
            const int s2 = csr[j + 2], s3 = csr[j + 3];
            const int s4 = csr[j + 4], s5 = csr[j + 5];
            const int s6 = csr[j + 6], s7 = csr[j + 7];
            const float4 u0 = *reinterpret_cast<const float4*>(yb + ((s0 << 4) + c4));
            const float4 u1 = *reinterpret_cast<const float4*>(yb + ((s1 << 4) + c4));
            const float4 u2 = *reinterpret_cast<const float4*>(yb + ((s2 << 4) + c4));
            const float4 u3 = *reinterpret_cast<const float4*>(yb + ((s3 << 4) + c4));
            const float4 u4 = *reinterpret_cast<const float4*>(yb + ((s4 << 4) + c4));
            const float4 u5 = *reinterpret_cast<const float4*>(yb + ((s5 << 4) + c4));
            const float4 u6 = *reinterpret_cast<const float4*>(yb + ((s6 << 4) + c4));
            const float4 u7 = *reinterpret_cast<const float4*>(yb + ((s7 << 4) + c4));
            addf4(acc, u0); addf4(acc, u1); addf4(acc, u2); addf4(acc, u3);
            addf4(acc, u4); addf4(acc, u5); addf4(acc, u6); addf4(acc, u7);
        }
        for (; j < end_; ++j) {
            const int s = csr[j];
            const float4 u = *reinterpret_cast<const float4*>(yb + ((s << 4) + c4));
            addf4(acc, u);
        }
        if (g == 0) tot1 = acc; else tot2 = acc;
    }

    const float4 yv = *reinterpret_cast<const float4*>(yb + ((v << 4) + c4));
    const float4 bb = *reinterpret_cast<const float4*>(b1 + sl * 16 + c4);
    const float a0 = attn[0], a1 = attn[1];
    float4 r;
    r.x = elu_f(a0 * (yv.x + tot1.x + bb.x)) + elu_f(a1 * (yv.x + tot2.x + bb.x));
    r.y = elu_f(a0 * (yv.y + tot1.y + bb.y)) + elu_f(a1 * (yv.y + tot2.y + bb.y));
    r.z = elu_f(a0 * (yv.z + tot1.z + bb.z)) + elu_f(a1 * (yv.z + tot2.z + bb.z));
    r.w = elu_f(a0 * (yv.w + tot1.w + bb.w)) + elu_f(a1 * (yv.w + tot2.w + bb.w));
    *reinterpret_cast<float4*>(x1 + (size_t)v * HIDDEN + sl * 16 + c4) = r;
}

// ---------------------------------------------------------------------------
// Pull layer 2, 16-dim-sliced f32 (4 slices), XCD-affine, same structure.
// slice = (blockIdx&7)>>1 — 2 XCDs per slice.
// ---------------------------------------------------------------------------
__global__ __launch_bounds__(256) void k_pull2(
    const float* __restrict__ y2s,
    const int* __restrict__ off, const int* __restrict__ csr,
    const float* __restrict__ b2, const float* __restrict__ attn,
    float* __restrict__ out)
{
    const int bid = blockIdx.x;
    const int sl = (bid & 7) >> 1;               // slice 0..3
    const int nb = (bid >> 3) * 2 + (bid & 1);   // node-block 0..781
    const int t = threadIdx.x;
    const int lane = t & 63;
    const int grp = lane >> 2;                   // node within wave 0..15
    const int c4 = (lane & 3) * 4;               // dims [c4,c4+4) of slice
    const int v = nb * 64 + (t >> 6) * 16 + grp;
    if (v >= N_NODES) return;
    const float* yb = y2s + ((size_t)sl * N_NODES << 4);

    float4 tot1 = {0.f, 0.f, 0.f, 0.f}, tot2 = {0.f, 0.f, 0.f, 0.f};
    #pragma unroll
    for (int g = 0; g < 2; ++g) {
        const int idx = g * N_NODES + v;
        const int beg = off[idx], end_ = off[idx + 1];
        float4 acc = {0.f, 0.f, 0.f, 0.f};
        int j = beg;
        for (; j + 8 <= end_; j += 8) {
            const int s0 = csr[j],     s1 = csr[j + 1];
            const int s2 = csr[j + 2], s3 = csr[j + 3];
            const int s4 = csr[j + 4], s5 = csr[j + 5];
            const int s6 = csr[j + 6], s7 = csr[j + 7];
            const float4 u0 = *reinterpret_cast<const float4*>(yb + ((s0 << 4) + c4));
            const float4 u1 = *reinterpret_cast<const float4*>(yb + ((s1 << 4) + c4));
            const float4 u2 = *reinterpret_cast<const float4*>(yb + ((s2 << 4) + c4));
            const float4 u3 = *reinterpret_cast<const float4*>(yb + ((s3 << 4) + c4));
            const float4 u4 = *reinterpret_cast<const float4*>(yb + ((s4 << 4) + c4));
            const float4 u5 = *reinterpret_cast<const float4*>(yb + ((s5 << 4) + c4));
            const float4 u6 = *reinterpret_cast<const float4*>(yb + ((s6 << 4) + c4));
            const float4 u7 = *reinterpret_cast<const float4*>(yb + ((s7 << 4) + c4));
            addf4(acc, u0); addf4(acc, u1); addf4(acc, u2); addf4(acc, u3);
            addf4(acc, u4); addf4(acc, u5); addf4(acc, u6); addf4(acc, u7);
        }
        for (; j < end_; ++j) {
            const int s = csr[j];
            const float4 u = *reinterpret_cast<const float4*>(yb + ((s << 4) + c4));
            addf4(acc, u);
        }
        if (g == 0) tot1 = acc; else tot2 = acc;
    }

    const float4 yv = *reinterpret_cast<const float4*>(yb + ((v << 4) + c4));
    const float4 bb = *reinterpret_cast<const float4*>(b2 + sl * 16 + c4);
    const float a0 = attn[0], a1 = attn[1];
    float4 r;
    r.x = elu_f(a0 * (yv.x + tot1.x + bb.x)) + elu_f(a1 * (yv.x + tot2.x + bb.x));
    r.y = elu_f(a0 * (yv.y + tot1.y + bb.y)) + elu_f(a1 * (yv.y + tot2.y + bb.y));
    r.z = elu_f(a0 * (yv.z + tot1.z + bb.z)) + elu_f(a1 * (yv.z + tot2.z + bb.z));
    r.w = elu_f(a0 * (yv.w + tot1.w + bb.w)) + elu_f(a1 * (yv.w + tot2.w + bb.w));
    *reinterpret_cast<float4*>(out + (size_t)v * CLASSES + sl * 16 + c4) = r;
}

extern "C" void kernel_launch(void* const* d_in, const int* in_sizes, int n_in,
                              void* d_out, int out_size, void* d_ws, size_t ws_size,
                              hipStream_t stream)
{
    const float* features = (const float*)d_in[0];
    const float* W1   = (const float*)d_in[1];
    const float* b1   = (const float*)d_in[2];
    const float* W2   = (const float*)d_in[3];
    const float* b2   = (const float*)d_in[4];
    const float* attn = (const float*)d_in[5];
    const int* src1   = (const int*)d_in[6];
    const int* dst1   = (const int*)d_in[7];
    const int* src2   = (const int*)d_in[8];
    const int* dst2   = (const int*)d_in[9];
    float* out = (float*)d_out;

    // workspace layout (binned aliases y1s — CSR build finishes before GEMM1)
    float* x1  = (float*)d_ws;                                  // 6.4M f32 = 25.6 MB
    float* y1s = x1 + (size_t)N_NODES * HIDDEN;                 // 6.4M f32 = 25.6 MB (8 slices)
    float* y2s = y1s + (size_t)N_NODES * HIDDEN;                // 3.2M f32 = 12.8 MB (4 slices)
    int* off      = (int*)(y2s + (size_t)N_NODES * CLASSES);    // N2+4
    int* binStart = off + (N2 + 4);                             // 392
    int* counts   = binStart + 392;                             // NB*NBLK
    int* csr      = counts + NB * NBLK;                         // 1.6M
    unsigned* binned = (unsigned*)y1s;                          // aliased, 1.6M

    // ---- binned CSR build (shared by both layers) ----
    k_p1_count  <<<NBLK, 1024, 0, stream>>>(dst1, dst2, counts);
    k_scan_bins <<<1, 512, 0, stream>>>(counts, binStart, off);
    k_p2_scatter<<<NBLK, 1024, 0, stream>>>(src1, dst1, src2, dst2, counts, binned);
    k_p3_csr    <<<NB, 1024, 0, stream>>>(binned, binStart, off, csr);

    // ---- layer 1 ----
    k_gemm1<<<GBLK, 256, 0, stream>>>(features, W1, y1s);
    k_pull1<<<6256, 256, 0, stream>>>(y1s, off, csr, b1, attn, x1);

    // ---- layer 2 ----
    k_gemm2<<<GBLK, 256, 0, stream>>>(x1, W2, y2s);
    k_pull2<<<3128, 256, 0, stream>>>(y2s, off, csr, b2, attn, out);
}